// Round 1
// baseline (33298.364 us; speedup 1.0000x reference)
//
#include <hip/hip_runtime.h>
#include <math.h>

#define B  64
#define T  256
#define S  512
#define IN 512
#define H  512
#define P  256
#define C  512

__device__ __forceinline__ float sigm(float x) { return 1.f / (1.f + __expf(-x)); }

// ---------------------------------------------------------------------------
// Fused GEMM: out[b, j] = sum_k A(b,k) * W(j,k) (+bias) with A = concat of up
// to 3 row-major sources. A tile staged transposed in LDS (conflict-free
// compute reads), W tile staged in LDS (wave-uniform broadcast reads).
// MODE 0: LSTM epilogue (j = gate*H + h; blocks tile h by 2; writes h,c)
// MODE 1: plain store to out0[b*C + j]            (q = h1 @ WattT)
// MODE 2: tanh, dual store dec_out + feed         (projection)
// ---------------------------------------------------------------------------
template<int MODE, int JT>
__global__ __launch_bounds__(256)
void gemm_fused(const float* __restrict__ A0, long s0, int l0, const float* __restrict__ W0, int ldw0, int ofs0,
                const float* __restrict__ A1, long s1, int l1, const float* __restrict__ W1, int ldw1, int ofs1,
                const float* __restrict__ A2, long s2, int l2, const float* __restrict__ W2, int ldw2, int ofs2,
                const float* __restrict__ bias0, const float* __restrict__ bias1,
                float* __restrict__ out0, float* __restrict__ out1, int t)
{
    constexpr int JB = 4 * JT;             // j outputs per block
    __shared__ float Alds[64 * 65];        // [kk][b] transposed, padded
    __shared__ float Wlds[JB * 64];        // [jj][kk]

    const int tid  = threadIdx.x;
    const int lane = tid & 63;             // = batch b for compute
    const int wave = tid >> 6;             // 0..3
    const int nch  = (l0 + l1 + l2) >> 6;  // 64-k chunks

    float acc[JT];
#pragma unroll
    for (int j = 0; j < JT; ++j) acc[j] = 0.f;

    const int bs = tid >> 2;               // staging: batch row
    const int kq = tid & 3;                // staging: k quarter (16 k each)

    for (int cc = 0; cc < nch; ++cc) {
        const int kg = cc << 6;
        const float* Ap; long as; const float* Wp; int ldw, wofs, kl;
        if (kg < l0)            { Ap = A0; as = s0; Wp = W0; ldw = ldw0; wofs = ofs0; kl = kg; }
        else if (kg < l0 + l1)  { Ap = A1; as = s1; Wp = W1; ldw = ldw1; wofs = ofs1; kl = kg - l0; }
        else                    { Ap = A2; as = s2; Wp = W2; ldw = ldw2; wofs = ofs2; kl = kg - l0 - l1; }

        // stage A (transposed): 16 floats per thread
        {
            const float* src = Ap + (long)bs * as + kl + kq * 16;
            float4 v0 = *(const float4*)(src);
            float4 v1 = *(const float4*)(src + 4);
            float4 v2 = *(const float4*)(src + 8);
            float4 v3 = *(const float4*)(src + 12);
            const int kb = kq * 16;
            Alds[(kb+ 0)*65 + bs] = v0.x; Alds[(kb+ 1)*65 + bs] = v0.y;
            Alds[(kb+ 2)*65 + bs] = v0.z; Alds[(kb+ 3)*65 + bs] = v0.w;
            Alds[(kb+ 4)*65 + bs] = v1.x; Alds[(kb+ 5)*65 + bs] = v1.y;
            Alds[(kb+ 6)*65 + bs] = v1.z; Alds[(kb+ 7)*65 + bs] = v1.w;
            Alds[(kb+ 8)*65 + bs] = v2.x; Alds[(kb+ 9)*65 + bs] = v2.y;
            Alds[(kb+10)*65 + bs] = v2.z; Alds[(kb+11)*65 + bs] = v2.w;
            Alds[(kb+12)*65 + bs] = v3.x; Alds[(kb+13)*65 + bs] = v3.y;
            Alds[(kb+14)*65 + bs] = v3.z; Alds[(kb+15)*65 + bs] = v3.w;
        }
        // stage W tile
        if (JT == 2) {                     // JB=8: 2 floats/thread
            const int jj = tid >> 5, i2 = tid & 31;
            const int jrow = (MODE == 0) ? ((jj >> 1) * H + blockIdx.x * 2 + (jj & 1))
                                         : ((int)blockIdx.x * JB + jj);
            const float2 wv = *(const float2*)(Wp + (long)jrow * ldw + wofs + kl + i2 * 2);
            Wlds[jj * 64 + i2 * 2]     = wv.x;
            Wlds[jj * 64 + i2 * 2 + 1] = wv.y;
        } else {                           // JB=4: 1 float/thread
            const int jj = tid >> 6, i = tid & 63;
            const int jrow = (int)blockIdx.x * JB + jj;
            Wlds[jj * 64 + i] = Wp[(long)jrow * ldw + wofs + kl + i];
        }
        __syncthreads();

#pragma unroll
        for (int k4 = 0; k4 < 16; ++k4) {
            const float a0 = Alds[(k4*4 + 0)*65 + lane];
            const float a1 = Alds[(k4*4 + 1)*65 + lane];
            const float a2 = Alds[(k4*4 + 2)*65 + lane];
            const float a3 = Alds[(k4*4 + 3)*65 + lane];
#pragma unroll
            for (int jt = 0; jt < JT; ++jt) {
                const float4 w = *(const float4*)&Wlds[(wave * JT + jt) * 64 + k4 * 4];
                acc[jt] = fmaf(a0, w.x, fmaf(a1, w.y, fmaf(a2, w.z, fmaf(a3, w.w, acc[jt]))));
            }
        }
        __syncthreads();
    }

    if (MODE == 0) {
        // gates exchange in LDS, then LSTM pointwise
#pragma unroll
        for (int jt = 0; jt < JT; ++jt) {
            const int jj = wave * JT + jt;
            const int jrow = (jj >> 1) * H + blockIdx.x * 2 + (jj & 1);
            float v = acc[jt];
            if (bias0) v += bias0[jrow];
            if (bias1) v += bias1[jrow];
            Alds[jj * 64 + lane] = v;
        }
        __syncthreads();
        if (tid < 128) {
            const int hh = tid >> 6, b = tid & 63;
            const float gi = Alds[(0 * 2 + hh) * 64 + b];
            const float gf = Alds[(1 * 2 + hh) * 64 + b];
            const float gg = Alds[(2 * 2 + hh) * 64 + b];
            const float go = Alds[(3 * 2 + hh) * 64 + b];
            const int hidx = blockIdx.x * 2 + hh;
            const float cold = out1[(long)b * H + hidx];
            const float cn = sigm(gf) * cold + sigm(gi) * tanhf(gg);
            const float hn = sigm(go) * tanhf(cn);
            out1[(long)b * H + hidx] = cn;
            out0[(long)b * H + hidx] = hn;
        }
    } else if (MODE == 1) {
        const int jrow = (int)blockIdx.x * JB + wave;     // JT==1
        out0[(long)lane * C + jrow] = acc[0];             // q[b][c]
    } else {
        const int jrow = (int)blockIdx.x * JB + wave;     // JT==1
        float v = acc[0];
        if (bias0) v += bias0[jrow];
        v = tanhf(v);
        out0[((long)lane * T + t) * P + jrow] = v;        // dec_out[b][t][p]
        out1[(long)lane * P + jrow] = v;                  // feed[b][p]
    }
}

// ---------------------------------------------------------------------------
// One-pass online-softmax attention. One block per batch, 8 waves, each wave
// owns 64 source positions; ctx read exactly once. Writes normalized alpha
// to d_out and expected context to ws.
// ---------------------------------------------------------------------------
__global__ __launch_bounds__(512)
void attn_flash(const float* __restrict__ q, const float* __restrict__ ctx,
                const float* __restrict__ mask, float* __restrict__ ectx,
                float* __restrict__ att_out, int t)
{
    const int b = blockIdx.x;
    const int tid = threadIdx.x;
    const int lane = tid & 63;
    const int w = tid >> 6;                     // 0..7
    __shared__ float scores[S];
    __shared__ float ms[8], ss[8];
    __shared__ float es[8 * C];

    float qv[8];
    {
        const float4 qa = *(const float4*)(q + (long)b * C + lane * 8);
        const float4 qb = *(const float4*)(q + (long)b * C + lane * 8 + 4);
        qv[0]=qa.x; qv[1]=qa.y; qv[2]=qa.z; qv[3]=qa.w;
        qv[4]=qb.x; qv[5]=qb.y; qv[6]=qb.z; qv[7]=qb.w;
    }
    const float* cb = ctx + (long)b * S * C;
    float m = -1e30f, sum = 0.f;
    float ea[8];
#pragma unroll
    for (int i = 0; i < 8; ++i) ea[i] = 0.f;

    for (int s = w * 64; s < (w + 1) * 64; ++s) {
        const float* cp = cb + (long)s * C + lane * 8;
        const float4 c0 = *(const float4*)cp;
        const float4 c1 = *(const float4*)(cp + 4);
        const float cv[8] = {c0.x, c0.y, c0.z, c0.w, c1.x, c1.y, c1.z, c1.w};
        float part = 0.f;
#pragma unroll
        for (int i = 0; i < 8; ++i) part = fmaf(qv[i], cv[i], part);
#pragma unroll
        for (int off = 32; off; off >>= 1) part += __shfl_xor(part, off);
        const float sc = part + (mask[(long)b * S + s] - 1.f) * 1e9f;
        if (lane == 0) scores[s] = sc;
        const float mn  = fmaxf(m, sc);
        const float scl = __expf(m - mn);
        const float p   = __expf(sc - mn);
        sum = fmaf(sum, scl, p);
#pragma unroll
        for (int i = 0; i < 8; ++i) ea[i] = fmaf(ea[i], scl, p * cv[i]);
        m = mn;
    }
    if (lane == 0) { ms[w] = m; ss[w] = sum; }
#pragma unroll
    for (int i = 0; i < 8; ++i) es[w * C + lane * 8 + i] = ea[i];
    __syncthreads();

    float gm = ms[0];
#pragma unroll
    for (int k = 1; k < 8; ++k) gm = fmaxf(gm, ms[k]);
    float gs = 0.f;
#pragma unroll
    for (int k = 0; k < 8; ++k) gs += __expf(ms[k] - gm) * ss[k];
    const float inv = 1.f / gs;

    {   // ectx: c = tid
        float v = 0.f;
#pragma unroll
        for (int k = 0; k < 8; ++k) v += __expf(ms[k] - gm) * es[k * C + tid];
        ectx[(long)b * C + tid] = v * inv;
    }
    // alpha: s = tid
    att_out[((long)b * T + t) * S + tid] = __expf(scores[tid] - gm) * inv;
}

// WT[c*n + h] = W[h*n + c]
__global__ __launch_bounds__(256)
void transpose_mat(const float* __restrict__ W, float* __restrict__ WT, int n)
{
    __shared__ float tile[32][33];
    const int nb = n / 32;
    const int bx = blockIdx.x % nb, by = blockIdx.x / nb;
    const int tx = threadIdx.x % 32, ty = threadIdx.x / 32;   // ty 0..7
#pragma unroll
    for (int i = 0; i < 4; ++i)
        tile[ty + i * 8][tx] = W[(long)(by * 32 + ty + i * 8) * n + bx * 32 + tx];
    __syncthreads();
#pragma unroll
    for (int i = 0; i < 4; ++i)
        WT[(long)(bx * 32 + ty + i * 8) * n + by * 32 + tx] = tile[tx][ty + i * 8];
}

__global__ __launch_bounds__(256)
void zero_kernel(float* __restrict__ p, int n)
{
    const int i = blockIdx.x * 256 + threadIdx.x;
    if (i < n) p[i] = 0.f;
}

extern "C" void kernel_launch(void* const* d_in, const int* in_sizes, int n_in,
                              void* d_out, int out_size, void* d_ws, size_t ws_size,
                              hipStream_t stream)
{
    (void)in_sizes; (void)n_in; (void)out_size; (void)ws_size;
    const float* dec_input = (const float*)d_in[0];
    const float* ctx       = (const float*)d_in[1];
    const float* mask      = (const float*)d_in[2];
    const float* Wih0      = (const float*)d_in[3];
    const float* Whh0      = (const float*)d_in[4];
    const float* bih0      = (const float*)d_in[5];
    const float* bhh0      = (const float*)d_in[6];
    const float* Wih1      = (const float*)d_in[7];
    const float* Whh1      = (const float*)d_in[8];
    const float* bih1      = (const float*)d_in[9];
    const float* bhh1      = (const float*)d_in[10];
    const float* Watt      = (const float*)d_in[11];
    const float* Wproj     = (const float*)d_in[12];
    const float* bproj     = (const float*)d_in[13];
    float* out = (float*)d_out;
    float* ws  = (float*)d_ws;

    float* h0    = ws;                         // [2][B*H]
    float* c0    = ws + 2 * B * H;             // [B*H]
    float* h1    = ws + 3 * B * H;             // [2][B*H]
    float* c1    = ws + 5 * B * H;             // [B*H]
    float* feed  = ws + 6 * B * H;             // [B*P]
    float* q     = feed + B * P;               // [B*C]
    float* ectx  = q + B * C;                  // [B*C]
    float* WattT = ectx + B * C;               // [C*H]

    const int nzero = 6 * B * H + B * P;       // h0(2),c0,h1(2),c1,feed
    zero_kernel<<<(nzero + 255) / 256, 256, 0, stream>>>(ws, nzero);
    transpose_mat<<<256, 256, 0, stream>>>(Watt, WattT, 512);

    float* dec_out = out;
    float* att_out = out + (long)B * T * P;

    for (int t = 0; t < T; ++t) {
        const float* h0i = h0 + (t & 1) * B * H;
        float*       h0o = h0 + ((t + 1) & 1) * B * H;
        const float* h1i = h1 + (t & 1) * B * H;
        float*       h1o = h1 + ((t + 1) & 1) * B * H;

        // LSTM layer 0: x = [x_t | feed], plus h0 @ Whh0^T
        gemm_fused<0, 2><<<256, 256, 0, stream>>>(
            dec_input + (long)t * IN, (long)T * IN, IN, Wih0, IN + P, 0,
            feed, (long)P, P, Wih0, IN + P, IN,
            h0i, (long)H, H, Whh0, H, 0,
            bih0, bhh0, h0o, c0, t);

        // LSTM layer 1
        gemm_fused<0, 2><<<256, 256, 0, stream>>>(
            h0o, (long)H, H, Wih1, H, 0,
            h1i, (long)H, H, Whh1, H, 0,
            nullptr, 0, 0, nullptr, 0, 0,
            bih1, bhh1, h1o, c1, t);

        // q = h1 @ Watt  (via transposed Watt, row-major [c][h])
        gemm_fused<1, 1><<<128, 256, 0, stream>>>(
            h1o, (long)H, H, WattT, H, 0,
            nullptr, 0, 0, nullptr, 0, 0,
            nullptr, 0, 0, nullptr, 0, 0,
            nullptr, nullptr, q, nullptr, t);

        // attention: scores, softmax, expected context (ctx read once)
        attn_flash<<<64, 512, 0, stream>>>(q, ctx, mask, ectx, att_out, t);

        // projection: res = tanh([h1 | ectx] @ Wproj^T + bproj) -> dec_out, feed
        gemm_fused<2, 1><<<64, 256, 0, stream>>>(
            h1o, (long)H, H, Wproj, H + C, 0,
            ectx, (long)C, C, Wproj, H + C, H,
            nullptr, 0, 0, nullptr, 0, 0,
            bproj, nullptr, dec_out, feed, t);
    }
}

// Round 3
// 20105.052 us; speedup vs baseline: 1.6562x; 1.6562x over previous
//
#include <hip/hip_runtime.h>
#include <math.h>

#define B  64
#define T  256
#define S  512
#define IN 512
#define H  512
#define P  256
#define C  512

typedef _Float16 f16x8 __attribute__((ext_vector_type(8)));
typedef float    f32x4 __attribute__((ext_vector_type(4)));
typedef unsigned short u16x8 __attribute__((ext_vector_type(8)));

#define MFMA16(a, b, c) __builtin_amdgcn_mfma_f32_16x16x32_f16(a, b, c, 0, 0, 0)

__device__ __forceinline__ float sigm(float x) { return 1.f / (1.f + __expf(-x)); }

// Split fp32 into fp16 hi + fp16 lo*4096 (scaled to keep lo in normal range).
__device__ __forceinline__ void split2(float v, unsigned short& hi, unsigned short& lo)
{
    _Float16 h = (_Float16)v;
    float r = (v - (float)h) * 4096.f;
    _Float16 l2 = (_Float16)r;
    union { _Float16 f; unsigned short u; } a, b2;
    a.f = h; b2.f = l2;
    hi = a.u; lo = b2.u;
}

// A-fragment layout (segment-local): element (row r in [0,64), k) lives at
// ushort index ((k>>5)*4 + (r>>4))*64*16 + lane*16 + (k&7), lane = ((k>>3)&3)*16 + (r&15).
// hi at +0, scaled-lo at +8. Consumer: wave reads dwordx4 at ((ks*4+mt)*64+l)*16.
__device__ __forceinline__ int frag_us(int r, int k)
{
    return ((((k >> 5) * 4 + (r >> 4)) * 64 + ((k >> 3) & 3) * 16 + (r & 15)) * 16) + (k & 7);
}

// ---------------------------------------------------------------------------
// LSTM GEMM: out[64 x 16cols] over K = NKS*32, fp16x2 3-term MFMA, no LDS in
// main loop. 4 waves split K 4-way; LDS reduce; LSTM pointwise epilogue.
// Columns are gate-interleaved p = h*4+g; block covers h in [blockIdx*4,+4).
// ---------------------------------------------------------------------------
template<int NKS>
__global__ __launch_bounds__(256)
void lstm_gemm(const unsigned short* __restrict__ A0, int n0,
               const unsigned short* __restrict__ A1, int n1,
               const unsigned short* __restrict__ A2,
               const unsigned short* __restrict__ Wf,
               const float* __restrict__ bias,
               float* __restrict__ cbuf,
               unsigned short* __restrict__ hfrag_out,
               float* __restrict__ hf32_out)
{
    __shared__ float red[4 * 64 * 20];
    const int tid = threadIdx.x;
    const int l   = tid & 63;
    const int kh  = tid >> 6;          // K-quarter owner
    const int ct  = blockIdx.x;        // 16-col tile index

    f32x4 acch[4] = {};
    f32x4 accl[4] = {};

    constexpr int KQ = NKS / 4;
#pragma unroll 2
    for (int i = 0; i < KQ; ++i) {
        const int ks = kh * KQ + i;
        const unsigned short* ap; int ksl;
        if (ks < n0)           { ap = A0; ksl = ks; }
        else if (ks < n0 + n1) { ap = A1; ksl = ks - n0; }
        else                   { ap = A2; ksl = ks - n0 - n1; }
        const f16x8* bp = (const f16x8*)(Wf + ((long)(ct * NKS + ks) * 64 + l) * 16);
        const f16x8 bh = bp[0];
        const f16x8 bl = bp[1];
#pragma unroll
        for (int mt = 0; mt < 4; ++mt) {
            const f16x8* app = (const f16x8*)(ap + ((ksl * 4 + mt) * 64 + l) * 16);
            const f16x8 ah = app[0];
            const f16x8 al = app[1];
            acch[mt] = MFMA16(ah, bh, acch[mt]);
            accl[mt] = MFMA16(ah, bl, accl[mt]);
            accl[mt] = MFMA16(al, bh, accl[mt]);
        }
    }

#pragma unroll
    for (int mt = 0; mt < 4; ++mt) {
        f32x4 v = acch[mt] + accl[mt] * (1.f / 4096.f);
        *(f32x4*)&red[(kh * 64 + l) * 20 + mt * 4] = v;
    }
    __syncthreads();

    // epilogue: thread = (b, hl); gates at cols hl*4+g
    const int b  = tid & 63;
    const int hl = tid >> 6;
    float g4[4];
#pragma unroll
    for (int g = 0; g < 4; ++g) {
        const int col = hl * 4 + g;
        const int li  = ((b & 15) >> 2) * 16 + col;   // lane holding (col, b)
        const int ri  = (b >> 4) * 4 + (b & 3);       // reg index (mt*4+reg)
        float v = bias[ct * 16 + col];
#pragma unroll
        for (int k2 = 0; k2 < 4; ++k2) v += red[(k2 * 64 + li) * 20 + ri];
        g4[g] = v;
    }
    const int hg = ct * 4 + hl;
    const float cold = cbuf[b * H + hg];
    const float cn = sigm(g4[1]) * cold + sigm(g4[0]) * tanhf(g4[2]);
    cbuf[b * H + hg] = cn;
    const float hn = sigm(g4[3]) * tanhf(cn);
    unsigned short hi, lo; split2(hn, hi, lo);
    const int fu = frag_us(b, hg);
    hfrag_out[fu]     = hi;
    hfrag_out[fu + 8] = lo;
    if (hf32_out) hf32_out[b * H + hg] = hn;
}

// ---------------------------------------------------------------------------
// Fused per-batch step: q = h1@Watt, flash attention (ctx read once, fp32),
// projection tanh([h1|ectx]@Wproj^T+b) -> dec_out + feed-frag, plus x_{t+1}
// fragment conversion. One block per batch, 512 threads.
// ---------------------------------------------------------------------------
__global__ __launch_bounds__(512)
void attn_step(const float* __restrict__ h1, const float* __restrict__ ctx,
               const float* __restrict__ mask, const float* __restrict__ Watt,
               const float* __restrict__ WprojT, const float* __restrict__ bproj,
               const float* __restrict__ dec_input,
               unsigned short* __restrict__ xfrag_next,
               unsigned short* __restrict__ feedfrag,
               float* __restrict__ dec_out, float* __restrict__ att_out, int t)
{
    __shared__ float hs[512];
    __shared__ float qv[512];
    __shared__ float qs[4][512];
    __shared__ float scores[512];
    __shared__ float ms[8], ss[8];
    __shared__ float es[8][512];
    __shared__ float ectxs[512];
    __shared__ float ps[8][256];

    const int b = blockIdx.x;
    const int tid = threadIdx.x;
    const int lane = tid & 63;
    const int w = tid >> 6;

    if (tid < 128) ((float4*)hs)[tid] = ((const float4*)(h1 + (long)b * H))[tid];
    __syncthreads();

    // ---- q[c] = sum_h hs[h] * Watt[h][c] ----
    {
        const int c4 = (tid & 127) * 4;
        const int kq = tid >> 7;                       // 0..3 (uniform per wave)
        float4 a = {0.f, 0.f, 0.f, 0.f};
#pragma unroll 4
        for (int kk = 0; kk < 128; ++kk) {
            const int k = kq * 128 + kk;
            const float4 wv = *(const float4*)(Watt + (long)k * C + c4);
            const float hk = hs[k];
            a.x = fmaf(hk, wv.x, a.x); a.y = fmaf(hk, wv.y, a.y);
            a.z = fmaf(hk, wv.z, a.z); a.w = fmaf(hk, wv.w, a.w);
        }
        *(float4*)&qs[kq][c4] = a;
    }
    __syncthreads();
    qv[tid] = qs[0][tid] + qs[1][tid] + qs[2][tid] + qs[3][tid];
    __syncthreads();

    // ---- flash attention over S, ctx read once ----
    float qr[8];
    {
        const float4 qa = *(const float4*)&qv[lane * 8];
        const float4 qb = *(const float4*)&qv[lane * 8 + 4];
        qr[0]=qa.x; qr[1]=qa.y; qr[2]=qa.z; qr[3]=qa.w;
        qr[4]=qb.x; qr[5]=qb.y; qr[6]=qb.z; qr[7]=qb.w;
    }
    const float* cb = ctx + (long)b * S * C;
    float m = -1e30f, sum = 0.f;
    float ea[8];
#pragma unroll
    for (int i = 0; i < 8; ++i) ea[i] = 0.f;

    for (int s = w * 64; s < (w + 1) * 64; ++s) {
        const float* cp = cb + (long)s * C + lane * 8;
        const float4 c0 = *(const float4*)cp;
        const float4 c1 = *(const float4*)(cp + 4);
        const float cv[8] = {c0.x, c0.y, c0.z, c0.w, c1.x, c1.y, c1.z, c1.w};
        float part = 0.f;
#pragma unroll
        for (int i = 0; i < 8; ++i) part = fmaf(qr[i], cv[i], part);
#pragma unroll
        for (int off = 32; off; off >>= 1) part += __shfl_xor(part, off);
        const float sc = part + (mask[(long)b * S + s] - 1.f) * 1e9f;
        if (lane == 0) scores[s] = sc;
        const float mn  = fmaxf(m, sc);
        const float scl = __expf(m - mn);
        const float p   = __expf(sc - mn);
        sum = fmaf(sum, scl, p);
#pragma unroll
        for (int i = 0; i < 8; ++i) ea[i] = fmaf(ea[i], scl, p * cv[i]);
        m = mn;
    }
    if (lane == 0) { ms[w] = m; ss[w] = sum; }
#pragma unroll
    for (int i = 0; i < 8; ++i) es[w][lane * 8 + i] = ea[i];
    __syncthreads();

    float gm = ms[0];
#pragma unroll
    for (int k = 1; k < 8; ++k) gm = fmaxf(gm, ms[k]);
    float gs = 0.f;
#pragma unroll
    for (int k = 0; k < 8; ++k) gs += __expf(ms[k] - gm) * ss[k];
    const float inv = 1.f / gs;

    {
        float v = 0.f;
#pragma unroll
        for (int k = 0; k < 8; ++k) v += __expf(ms[k] - gm) * es[k][tid];
        ectxs[tid] = v * inv;
    }
    att_out[((long)b * T + t) * S + tid] = __expf(scores[tid] - gm) * inv;
    __syncthreads();

    // ---- projection: out[p] = tanh( sum_k cat[k]*WprojT[k][p] + bproj[p] ) ----
    {
        const int c4 = (tid & 63) * 4;
        const int kq = tid >> 6;                       // 0..7 == wave (uniform)
        float4 a = {0.f, 0.f, 0.f, 0.f};
#pragma unroll 4
        for (int kk = 0; kk < 128; ++kk) {
            const int k = kq * 128 + kk;
            const float op = (kq < 4) ? hs[k] : ectxs[k - 512];
            const float4 wv = *(const float4*)(WprojT + (long)k * P + c4);
            a.x = fmaf(op, wv.x, a.x); a.y = fmaf(op, wv.y, a.y);
            a.z = fmaf(op, wv.z, a.z); a.w = fmaf(op, wv.w, a.w);
        }
        *(float4*)&ps[kq][c4] = a;
    }
    __syncthreads();
    if (tid < 256) {
        const int p = tid;
        float v = bproj[p];
#pragma unroll
        for (int k = 0; k < 8; ++k) v += ps[k][p];
        v = tanhf(v);
        dec_out[((long)b * T + t) * P + p] = v;
        unsigned short hi, lo; split2(v, hi, lo);
        const int fu = frag_us(b, p);
        feedfrag[fu]     = hi;
        feedfrag[fu + 8] = lo;
    }
    // ---- x_{t+1} -> fragment layout ----
    if (t + 1 < T) {
        const int k = tid;
        unsigned short hi, lo;
        split2(dec_input[((long)b * T + (t + 1)) * IN + k], hi, lo);
        const int fu = frag_us(b, k);
        xfrag_next[fu]     = hi;
        xfrag_next[fu + 8] = lo;
    }
}

// ---------------------------------------------------------------------------
// One-time prep: zero state, x0 fragments, combined biases, WprojT, and
// gate-interleaved fp16x2 weight fragments.
// ---------------------------------------------------------------------------
__global__ __launch_bounds__(256)
void prep_all(const float* __restrict__ dec_input,
              const float* __restrict__ Wih0, const float* __restrict__ Whh0,
              const float* __restrict__ bih0, const float* __restrict__ bhh0,
              const float* __restrict__ Wih1, const float* __restrict__ Whh1,
              const float* __restrict__ bih1, const float* __restrict__ bhh1,
              const float* __restrict__ Wproj,
              float* __restrict__ zbase,
              unsigned short* __restrict__ xf0,
              float* __restrict__ bcat0, float* __restrict__ bcat1,
              float* __restrict__ WprojT,
              unsigned short* __restrict__ W0f, unsigned short* __restrict__ W1f)
{
    const int bid = blockIdx.x, tid = threadIdx.x;
    if (bid < 144) {                                   // zero 589824 B
        float4 z = {0.f, 0.f, 0.f, 0.f};
        ((float4*)zbase)[bid * 256 + tid] = z;
    } else if (bid < 272) {                            // x0 fragments
        const int idx = (bid - 144) * 256 + tid;       // 0..32767
        const int bb = idx >> 9, k = idx & 511;
        unsigned short hi, lo;
        split2(dec_input[((long)bb * T) * IN + k], hi, lo);
        const int fu = frag_us(bb, k);
        xf0[fu] = hi; xf0[fu + 8] = lo;
    } else if (bid < 288) {                            // combined biases
        const int idx = (bid - 272) * 256 + tid;       // 0..4095
        if (idx < 2048) {
            const int p = idx, h = p >> 2, g = p & 3, orig = g * H + h;
            bcat0[p] = bih0[orig] + bhh0[orig];
        } else {
            const int p = idx - 2048, h = p >> 2, g = p & 3, orig = g * H + h;
            bcat1[p] = bih1[orig] + bhh1[orig];
        }
    } else if (bid < 1312) {                           // WprojT fp32 [1024][256]
        const int idx = (bid - 288) * 256 + tid;       // 0..262143
        const int k = idx >> 8, p = idx & 255;
        WprojT[k * P + p] = Wproj[(long)p * (H + C) + k];
    } else if (bid < 2592) {                           // W0 fragments (NKS=40)
        const int idx = (bid - 1312) * 256 + tid;      // 0..327679
        const int n = idx / 160, k8 = idx - n * 160;
        const int k = k8 * 8;
        const int h = n >> 2, g = n & 3, orig = g * H + h;
        const float* src = (k < IN + P) ? (Wih0 + (long)orig * (IN + P) + k)
                                        : (Whh0 + (long)orig * H + (k - (IN + P)));
        u16x8 hv, lv;
#pragma unroll
        for (int j = 0; j < 8; ++j) {
            unsigned short hi, lo; split2(src[j], hi, lo);
            hv[j] = hi; lv[j] = lo;
        }
        const long base = ((long)((n >> 4) * 40 + (k >> 5)) * 64 + ((k >> 3) & 3) * 16 + (n & 15)) * 16;
        *(u16x8*)(W0f + base)     = hv;
        *(u16x8*)(W0f + base + 8) = lv;
    } else {                                           // W1 fragments (NKS=32)
        const int idx = (bid - 2592) * 256 + tid;      // 0..262143
        const int n = idx >> 7, k8 = idx & 127;
        const int k = k8 * 8;
        const int h = n >> 2, g = n & 3, orig = g * H + h;
        const float* src = (k < H) ? (Wih1 + (long)orig * H + k)
                                   : (Whh1 + (long)orig * H + (k - H));
        u16x8 hv, lv;
#pragma unroll
        for (int j = 0; j < 8; ++j) {
            unsigned short hi, lo; split2(src[j], hi, lo);
            hv[j] = hi; lv[j] = lo;
        }
        const long base = ((long)((n >> 4) * 32 + (k >> 5)) * 64 + ((k >> 3) & 3) * 16 + (n & 15)) * 16;
        *(u16x8*)(W1f + base)     = hv;
        *(u16x8*)(W1f + base + 8) = lv;
    }
}

extern "C" void kernel_launch(void* const* d_in, const int* in_sizes, int n_in,
                              void* d_out, int out_size, void* d_ws, size_t ws_size,
                              hipStream_t stream)
{
    (void)in_sizes; (void)n_in; (void)out_size; (void)ws_size;
    const float* dec_input = (const float*)d_in[0];
    const float* ctx       = (const float*)d_in[1];
    const float* mask      = (const float*)d_in[2];
    const float* Wih0      = (const float*)d_in[3];
    const float* Whh0      = (const float*)d_in[4];
    const float* bih0      = (const float*)d_in[5];
    const float* bhh0      = (const float*)d_in[6];
    const float* Wih1      = (const float*)d_in[7];
    const float* Whh1      = (const float*)d_in[8];
    const float* bih1      = (const float*)d_in[9];
    const float* bhh1      = (const float*)d_in[10];
    const float* Watt      = (const float*)d_in[11];
    const float* Wproj     = (const float*)d_in[12];
    const float* bproj     = (const float*)d_in[13];
    float* out = (float*)d_out;
    char*  wsb = (char*)d_ws;

    // ws layout (bytes); first 589824 B are the zero region
    float*          c0    = (float*)(wsb + 0);                 // 131072
    float*          c1    = (float*)(wsb + 131072);            // 131072
    unsigned short* h0f0  = (unsigned short*)(wsb + 262144);   // 131072
    unsigned short* h1f0  = (unsigned short*)(wsb + 393216);   // 131072
    unsigned short* feedf = (unsigned short*)(wsb + 524288);   // 65536
    unsigned short* h0f1  = (unsigned short*)(wsb + 589824);   // 131072
    unsigned short* h1f1  = (unsigned short*)(wsb + 720896);   // 131072
    float*          h1f32 = (float*)(wsb + 851968);            // 131072
    unsigned short* xf0   = (unsigned short*)(wsb + 983040);   // 131072
    unsigned short* xf1   = (unsigned short*)(wsb + 1114112);  // 131072
    float*          bcat0 = (float*)(wsb + 1245184);           // 8192
    float*          bcat1 = (float*)(wsb + 1253376);           // 8192
    float*          WprojT= (float*)(wsb + 1261568);           // 1048576
    unsigned short* W0f   = (unsigned short*)(wsb + 2310144);  // 10485760
    unsigned short* W1f   = (unsigned short*)(wsb + 12795904); // 8388608
    // total 21184512 B

    prep_all<<<3616, 256, 0, stream>>>(dec_input, Wih0, Whh0, bih0, bhh0,
                                       Wih1, Whh1, bih1, bhh1, Wproj,
                                       (float*)wsb, xf0, bcat0, bcat1, WprojT, W0f, W1f);

    unsigned short* h0fr[2] = {h0f0, h0f1};
    unsigned short* h1fr[2] = {h1f0, h1f1};
    unsigned short* xfr[2]  = {xf0, xf1};

    float* dec_out = out;
    float* att_out = out + (long)B * T * P;

    for (int t = 0; t < T; ++t) {
        unsigned short* h0_in  = h0fr[t & 1];
        unsigned short* h0_out = h0fr[(t + 1) & 1];
        unsigned short* h1_in  = h1fr[t & 1];
        unsigned short* h1_out = h1fr[(t + 1) & 1];

        // LSTM layer 0: A = [x_t(16ks) | feed(8ks) | h0(16ks)], K = 1280
        lstm_gemm<40><<<128, 256, 0, stream>>>(
            xfr[t & 1], 16, feedf, 8, h0_in, W0f, bcat0, c0, h0_out, nullptr);

        // LSTM layer 1: A = [h0_new(16ks) | h1(16ks)], K = 1024
        lstm_gemm<32><<<128, 256, 0, stream>>>(
            h0_out, 16, h1_in, 16, nullptr, W1f, bcat1, c1, h1_out, h1f32);

        // q + attention + projection (+ x_{t+1} conversion)
        attn_step<<<64, 512, 0, stream>>>(
            h1f32, ctx, mask, Watt, WprojT, bproj, dec_input,
            xfr[(t + 1) & 1], feedf, dec_out, att_out, t);
    }
}